// Round 17
// baseline (172.467 us; speedup 1.0000x reference)
//
#include <hip/hip_runtime.h>

// Problem constants
#define NB   4
#define NH   12
#define HD   64
#define CCH  768        // NH*HD
#define LQ   1024
#define SCALE 0.125f    // 1/sqrt(64)
#define STAB  4.0f      // constant softmax stabilizer (scores ~N(0,1), max~4)
#define SC2  0.18033688f  // SCALE * log2(e)
#define ST2  5.7707802f   // STAB  * log2(e)
#define WELE (CCH*CCH)  // 589824 elements per weight matrix

typedef unsigned short u16;
typedef __bf16 bf16x8 __attribute__((ext_vector_type(8)));
typedef unsigned short u16x8 __attribute__((ext_vector_type(8)));
typedef unsigned short u16x4 __attribute__((ext_vector_type(4)));
typedef float floatx4 __attribute__((ext_vector_type(4)));

__device__ __forceinline__ float bf2f(u16 u) {
    union { unsigned int i; float f; } x; x.i = ((unsigned int)u) << 16; return x.f;
}
__device__ __forceinline__ u16 f2bf_u(float f) {
    union { float f; unsigned int i; } x; x.f = f;
    unsigned int i = x.i;
    return (u16)((i + 0x7FFFu + ((i >> 16) & 1u)) >> 16);   // RNE
}
// pack 2 f32 -> 2 bf16 (RNE), single HW instr (no builtin on gfx950; src0->lo)
__device__ __forceinline__ unsigned int cvt_pk_bf16(float a, float b) {
    unsigned int r;
    asm("v_cvt_pk_bf16_f32 %0, %1, %2" : "=v"(r) : "v"(a), "v"(b));
    return r;
}
// async global -> LDS, 16 B per lane; lds dst must be wave-uniform base
__device__ __forceinline__ void glds16(const u16* g, u16* l) {
    __builtin_amdgcn_global_load_lds(
        (const __attribute__((address_space(1))) unsigned int*)g,
        (__attribute__((address_space(3))) unsigned int*)l, 16, 0, 0);
}

// ---------------------------------------------------------------------------
// prep kernel: fused weight-convert + x-transpose (saves one launch gap).
//   blk <  768 : x [b][c][l] fp32 -> xT [b][l][c] bf16 (64x64 LDS transpose)
//   blk >= 768 : fp32 -> bf16 weight convert ([4][768*768]: wq,wk,wv,wo)
// ---------------------------------------------------------------------------
__global__ __launch_bounds__(256) void prep_kernel(
    const float* __restrict__ x,
    const float* __restrict__ wq, const float* __restrict__ wk,
    const float* __restrict__ wv, const float* __restrict__ wo,
    u16* __restrict__ wb, u16* __restrict__ xT)
{
    const int blk = blockIdx.x;
    const int t = threadIdx.x;
    if (blk < 768) {
        __shared__ u16 tile[64 * 68];
        const int l0 = (blk % 16) * 64, c0 = ((blk / 16) % 12) * 64, b = blk / 192;
        const float* xb = x + (size_t)b * CCH * LQ;
        {
            const int l = t & 63, cg = t >> 6;
            for (int i = 0; i < 16; ++i) {
                const int c = cg * 16 + i;
                tile[c * 68 + l] = f2bf_u(xb[(size_t)(c0 + c) * LQ + l0 + l]);
            }
        }
        __syncthreads();
        {
            const int c = t & 63, lg = t >> 6;
            for (int i = 0; i < 16; ++i) {
                const int l = lg * 16 + i;
                xT[((size_t)b * LQ + l0 + l) * CCH + c0 + c] = tile[c * 68 + l];
            }
        }
    } else {
        const int blk2 = blk - 768;
        const int p = blk2 / 576, bxi = blk2 % 576;
        const float* src = (p == 0) ? wq : (p == 1) ? wk : (p == 2) ? wv : wo;
        u16* dst = wb + (size_t)p * WELE;
        const int idx = (bxi * 256 + t) * 4;
        const float4 v = *reinterpret_cast<const float4*>(src + idx);
        u16x4 o;
        o[0] = f2bf_u(v.x); o[1] = f2bf_u(v.y); o[2] = f2bf_u(v.z); o[3] = f2bf_u(v.w);
        *reinterpret_cast<u16x4*>(dst + idx) = o;
    }
}

// ---------------------------------------------------------------------------
// Tiled MFMA GEMM core: Y = A (M x K) . B^T (N x K), both bf16 row-major-in-K.
// CTA (MI*32) x 128, BK=64, 8 waves (512 thr). glds16 staging, XOR-8 chunk
// swizzle, double-buffered, ONE barrier per K-step. Waves 2(m) x 4(n);
// wave tile (MI*16) x 32.  MI=2 -> 64x128 (LDS 48K, 3 CTA/CU = 24 waves/CU).
// ---------------------------------------------------------------------------
#define GEMM_STAGE(Ag, Bg, k0, abuf, bbuf, MI)                                \
    {                                                                         \
        _Pragma("unroll") for (int i = 0; i < (MI / 2); ++i) {                \
            const int sbase = (wave * (MI / 2) + i) * 64;                     \
            const int s = sbase + lane;                                       \
            const int m = s >> 3, pos = s & 7;                                \
            const int gpos = pos ^ (m & 7);                                   \
            glds16(Ag + (size_t)(m0 + m) * CCH + (k0) + gpos * 8,             \
                   &(abuf)[sbase * 8]);                                       \
        }                                                                     \
        _Pragma("unroll") for (int i = 0; i < 2; ++i) {                       \
            const int sbase = (wave * 2 + i) * 64;                            \
            const int s = sbase + lane;                                       \
            const int m = s >> 3, pos = s & 7;                                \
            const int gpos = pos ^ (m & 7);                                   \
            glds16(Bg + (size_t)(n0 + m) * CCH + (k0) + gpos * 8,             \
                   &(bbuf)[sbase * 8]);                                       \
        }                                                                     \
    }

#define GEMM_CORE(Ag, Bg, MI)                                                 \
    __shared__ __align__(16) u16 a_tile[2][(MI * 32) * 64];                   \
    __shared__ __align__(16) u16 b_tile[2][128 * 64];                         \
    const int t = threadIdx.x;                                                \
    const int wave = t >> 6, lane = t & 63;                                   \
    const int quad = lane >> 4, l16 = lane & 15;                              \
    const int wm = (wave >> 2) * (MI * 16), wn = (wave & 3) * 32;             \
    floatx4 acc[MI][2];                                                       \
    _Pragma("unroll") for (int mi = 0; mi < MI; ++mi)                         \
        _Pragma("unroll") for (int ni = 0; ni < 2; ++ni)                      \
            _Pragma("unroll") for (int r = 0; r < 4; ++r) acc[mi][ni][r] = 0.f;\
    GEMM_STAGE(Ag, Bg, 0, a_tile[0], b_tile[0], MI)                           \
    for (int kk = 0; kk < CCH / 64; ++kk) {                                   \
        __syncthreads();                                                      \
        if (kk + 1 < CCH / 64)                                                \
            GEMM_STAGE(Ag, Bg, (kk + 1) * 64,                                 \
                       a_tile[(kk + 1) & 1], b_tile[(kk + 1) & 1], MI)        \
        const u16* at = a_tile[kk & 1];                                       \
        const u16* bt = b_tile[kk & 1];                                       \
        bf16x8 af[2][MI], bfr[2][2];                                          \
        _Pragma("unroll") for (int s = 0; s < 2; ++s) {                       \
            _Pragma("unroll") for (int i = 0; i < MI; ++i) {                  \
                const int am = wm + i * 16 + l16;                             \
                const int c = s * 4 + quad;                                   \
                af[s][i]  = *reinterpret_cast<const bf16x8*>(                 \
                    &at[(am * 8 + (c ^ (am & 7))) * 8]);                      \
            }                                                                 \
            _Pragma("unroll") for (int j = 0; j < 2; ++j) {                   \
                const int bn = wn + j * 16 + l16;                             \
                const int c = s * 4 + quad;                                   \
                bfr[s][j] = *reinterpret_cast<const bf16x8*>(                 \
                    &bt[(bn * 8 + (c ^ (bn & 7))) * 8]);                      \
            }                                                                 \
        }                                                                     \
        _Pragma("unroll") for (int s = 0; s < 2; ++s)                         \
            _Pragma("unroll") for (int mi = 0; mi < MI; ++mi)                 \
                _Pragma("unroll") for (int ni = 0; ni < 2; ++ni)              \
                    acc[mi][ni] = __builtin_amdgcn_mfma_f32_16x16x32_bf16(    \
                        af[s][mi], bfr[s][ni], acc[mi][ni], 0, 0, 0);         \
    }

// proj_qkv (MI=2 M-split: 1152 CTAs, 3 CTA/CU, 24 waves/CU):
//   p==0 (Q), p==2 (V): A = wb[p] (o x c), B^T = xT[b] (l x c) -> Y [b][o][l]
//       96 tiles/GEMM = 12 M-tiles(64) x 8 N-tiles(128)
//   p==1 (K):           A = xT[b] (l x c), B^T = wb[1] (o x c) -> Kt [b][l][o]
//       96 tiles/GEMM = 16 M-tiles(64) x 6 N-tiles(128)
//   Chunked XCD swizzle (1152 = 8*144).
__global__ __launch_bounds__(512, 6) void proj_qkv_kernel(
    const u16* __restrict__ xT, const u16* __restrict__ wb,
    const float* __restrict__ bq, const float* __restrict__ bk,
    const float* __restrict__ bv,
    u16* __restrict__ Qw, u16* __restrict__ Kw, u16* __restrict__ Vw)
{
    const int wg0 = blockIdx.x + 8 * (blockIdx.y + 12 * blockIdx.z);
    const int swz = (wg0 & 7) * 144 + (wg0 >> 3);
    const int z = swz / 96, q = swz % 96;
    const int b = z / 3, p = z % 3;
    int m0, n0;
    const u16 *Ag, *Bg;
    if (p == 1) {
        m0 = (q / 6) * 64;                // L rows  (16 tiles)
        n0 = (q % 6) * 128;               // C cols  (6 tiles)
        Ag = xT + (size_t)b * LQ * CCH;
        Bg = wb + (size_t)WELE;
    } else {
        m0 = (q / 8) * 64;                // C rows  (12 tiles)
        n0 = (q % 8) * 128;               // L cols  (8 tiles)
        Ag = wb + (size_t)p * WELE;
        Bg = xT + (size_t)b * LQ * CCH;
    }

    GEMM_CORE(Ag, Bg, 2)

    if (p == 1) {
        u16* Y = Kw + (size_t)b * LQ * CCH;      // Kt [l][c]
#pragma unroll
        for (int mi = 0; mi < 2; ++mi) {
#pragma unroll
            for (int r = 0; r < 4; ++r) {
                const int l = m0 + wm + mi * 16 + quad * 4 + r;
#pragma unroll
                for (int ni = 0; ni < 2; ++ni) {
                    const int o = n0 + wn + ni * 16 + l16;
                    Y[(size_t)l * CCH + o] = f2bf_u(acc[mi][ni][r] + bk[o]);
                }
            }
        }
    } else {
        const float* bias = (p == 0) ? bq : bv;
        u16* Y = ((p == 0) ? Qw : Vw) + (size_t)b * CCH * LQ;
#pragma unroll
        for (int mi = 0; mi < 2; ++mi) {
#pragma unroll
            for (int r = 0; r < 4; ++r) {
                const int o = m0 + wm + mi * 16 + quad * 4 + r;
                const float bb = bias[o];
#pragma unroll
                for (int ni = 0; ni < 2; ++ni) {
                    const int l = n0 + wn + ni * 16 + l16;
                    Y[(size_t)o * LQ + l] = f2bf_u(acc[mi][ni][r] + bb);
                }
            }
        }
    }
}

// proj_out: A = wb[3], B^T = resb[b] ([l][c] bf16); out fp32 [b][c][l]
// M-split 64x128 tile (MI=2): 12 x 8 x 4 = 384 CTAs -> every CU covered.
__global__ __launch_bounds__(512) void proj_out_kernel(
    const u16* __restrict__ resb, const u16* __restrict__ wb,
    const float* __restrict__ bo, float* __restrict__ out)
{
    const int wg0 = blockIdx.x + 8 * (blockIdx.y + 12 * blockIdx.z);
    const int swz = (wg0 & 7) * 48 + (wg0 >> 3);
    const int bx = swz % 8, rest = swz / 8;
    const int by = rest % 12, b = rest / 12;
    const int n0 = bx * 128, m0 = by * 64;
    const u16* Ag = wb + (size_t)3 * WELE;
    const u16* Bg = resb + (size_t)b * LQ * CCH;
    float* Y = out + (size_t)b * CCH * LQ;

    GEMM_CORE(Ag, Bg, 2)

#pragma unroll
    for (int mi = 0; mi < 2; ++mi) {
#pragma unroll
        for (int r = 0; r < 4; ++r) {
            const int o = m0 + wm + mi * 16 + quad * 4 + r;
            const float bb = bo[o];
#pragma unroll
            for (int ni = 0; ni < 2; ++ni) {
                const int l = n0 + wn + ni * 16 + l16;
                Y[(size_t)o * LQ + l] = acc[mi][ni][r] + bb;
            }
        }
    }
}

// ---------------------------------------------------------------------------
// MFMA flash attention, S^T formulation + constant-stabilizer softmax.
//   (EXACT round-14 attn — QBLK=64, 4 waves, double-buffered; verified
//   52.8-53.7 us. Single-buffer variants raced (r15/r16, cause unidentified,
//   abandoned); QBLK=128 falsified (no HBM win, occupancy cost).)
//   K ([b][l][c] via proj swap) and V ([b][c][l]) staged via global_load_lds
//   into XOR-8-chunk-swizzled LDS, double-buffered, ONE barrier per iter.
//   XCD swizzle: all 16 q-blocks of one (b,h) land on one XCD (L2-resident).
//   p = exp2(s*SC2 - ST2); l accumulates per-lane; O accumulates with no
//   rescale (e^-STAB cancels in p/l). P via LDS (A-layout), PV = mfma(P, V).
// CTA = one (b,h) x 64 q-rows; 4 waves x 16 q. Key blocks of 64.
// ---------------------------------------------------------------------------
#define KSTRIDE 72
#define TILE_E  (64 * 64)   // u16 elements per K or V tile

// stage one 64x64 bf16 K tile + one 64x64 V tile: 16 glds16 calls split
// 4-per-wave (waves 0,1 -> K; waves 2,3 -> V). Chunk-swizzled source so the
// linear LDS destination holds chunk c of row m at slot c^(m&7).
__device__ __forceinline__ void stage_kv(
    const u16* __restrict__ Kb, const u16* __restrict__ Vb, int j0,
    u16* kb_lds, u16* vb_lds, int wave, int lane)
{
#pragma unroll
    for (int i = 0; i < 4; ++i) {
        const int sidx = wave * 4 + i;          // 0..15 (wave-uniform)
        if (sidx < 8) {
            const int sbase = sidx * 64;
            const int s = sbase + lane;
            const int m = s >> 3, pos = s & 7;  // key row, chunk slot
            const int gpos = pos ^ (m & 7);
            glds16(Kb + (size_t)(j0 + m) * CCH + gpos * 8, &kb_lds[sbase * 8]);
        } else {
            const int sbase = (sidx - 8) * 64;
            const int s = sbase + lane;
            const int m = s >> 3, pos = s & 7;  // d row, chunk slot
            const int gpos = pos ^ (m & 7);
            glds16(Vb + (size_t)m * LQ + j0 + gpos * 8, &vb_lds[sbase * 8]);
        }
    }
}

__global__ __launch_bounds__(256) void attn_kernel(
    const u16* __restrict__ Qw, const u16* __restrict__ Kt,
    const u16* __restrict__ Vw,
    const float* __restrict__ erk, const float* __restrict__ erv,
    u16* __restrict__ resb)
{
    __shared__ __align__(16) u16 kbuf[2 * TILE_E];   // [key][d] chunk-swizzled
    __shared__ __align__(16) u16 vbuf[2 * TILE_E];   // [d][key] chunk-swizzled
    __shared__ __align__(16) u16 p_lds[4 * 16 * KSTRIDE];
    __shared__ float bias_lds[64 * 9];
    __shared__ float bandw_lds[64 * 9];
    __shared__ float erk_lds[9 * 64];
    __shared__ float erv_lds[9 * 64];

    const int t = threadIdx.x;
    const int wave = t >> 6, lane = t & 63;
    const int quad = lane >> 4, l16 = lane & 15;
    // XCD-aware remap: q-blocks of one (b,h) share wgid residue mod 8
    const int wg = blockIdx.x + 16 * (blockIdx.y + 12 * blockIdx.z);
    const int rr = wg & 7, j = wg >> 3;
    const int l0 = (j & 15) * 64;
    const int hb = rr + 8 * (j >> 4);    // 0..47
    const int h = hb % NH, b = hb / NH;
    const int rbase = wave * 16;
    const size_t base = ((size_t)b * CCH + (size_t)h * HD) * LQ;
    const u16* Qb = Qw + base;
    const u16* Vb = Vw + base;
    const u16* Kb = Kt + (size_t)b * LQ * CCH + (size_t)h * HD;  // Kt rows

    for (int i = t; i < 9 * 64; i += 256) {
        erk_lds[i] = erk[(size_t)h * 9 * 64 + i];
        erv_lds[i] = erv[(size_t)h * 9 * 64 + i];
    }

    // Q frags (serve as MFMA B operand): lane holds q-row = l16, d = quad*8+jj (+32)
    bf16x8 qa0, qa1;
    {
        const int lg = l0 + rbase + l16;
        union { u16x8 u; bf16x8 v; } t0, t1;
#pragma unroll
        for (int jj = 0; jj < 8; ++jj) {
            t0.u[jj] = Qb[(size_t)(quad * 8 + jj) * LQ + lg];
            t1.u[jj] = Qb[(size_t)(32 + quad * 8 + jj) * LQ + lg];
        }
        qa0 = t0.v; qa1 = t1.v;
    }

    // prologue: stage tile 0 into buf0 (drains at the erk barrier / first loop barrier)
    stage_kv(Kb, Vb, 0, kbuf, vbuf, wave, lane);

    __syncthreads();   // erk_lds ready + tile0 staged

    // bias_lds[row][dl] = q_row . erk[dl]
    {
        union { bf16x8 v; u16x8 u; } a0, a1; a0.v = qa0; a1.v = qa1;
        float qf[16];
#pragma unroll
        for (int jj = 0; jj < 8; ++jj) { qf[jj] = bf2f(a0.u[jj]); qf[8 + jj] = bf2f(a1.u[jj]); }
        for (int dl = 0; dl < 9; ++dl) {
            float s = 0.f;
#pragma unroll
            for (int jj = 0; jj < 8; ++jj) {
                s += qf[jj]     * erk_lds[dl * 64 + quad * 8 + jj];
                s += qf[8 + jj] * erk_lds[dl * 64 + 32 + quad * 8 + jj];
            }
            s += __shfl_xor(s, 16, 64);
            s += __shfl_xor(s, 32, 64);
            if (quad == 0) bias_lds[(rbase + l16) * 9 + dl] = s;
        }
    }

    // O[tt][r]: q = quad*4+r (wave-local), d = tt*16+l16.  l_acc: per-lane
    // partial softmax denom for q = l16 over this lane's key subset.
    floatx4 O[4];
    float l_acc = 0.f;
#pragma unroll
    for (int i = 0; i < 4; ++i)
#pragma unroll
        for (int r = 0; r < 4; ++r) O[i][r] = 0.f;

    u16* pw = p_lds + wave * 16 * KSTRIDE;
    const int qrow = rbase + l16;          // this lane's softmax q-row
    const int lgq = l0 + qrow;

    for (int kb = 0; kb < 16; ++kb) {
        const int j0 = kb * 64;
        // barrier: tile kb staged (vmcnt0 before s_barrier) + prev reads done
        __syncthreads();
        if (kb < 15)
            stage_kv(Kb, Vb, j0 + 64,
                     kbuf + ((kb + 1) & 1) * TILE_E,
                     vbuf + ((kb + 1) & 1) * TILE_E, wave, lane);
        const u16* kt = kbuf + (kb & 1) * TILE_E;
        const u16* vt = vbuf + (kb & 1) * TILE_E;

        // S^T = K.Q^T: 4 key tiles; C row = key = quad*4+r, col = q = l16
        floatx4 s4[4];
#pragma unroll
        for (int tt = 0; tt < 4; ++tt) {
            const int row = tt * 16 + l16;
            const bf16x8 ka0 = *reinterpret_cast<const bf16x8*>(
                &kt[(row * 8 + (quad ^ (row & 7))) * 8]);
            const bf16x8 ka1 = *reinterpret_cast<const bf16x8*>(
                &kt[(row * 8 + ((quad + 4) ^ (row & 7))) * 8]);
            floatx4 c;
#pragma unroll
            for (int r = 0; r < 4; ++r) c[r] = 0.f;
            c = __builtin_amdgcn_mfma_f32_16x16x32_bf16(ka0, qa0, c, 0, 0, 0);
            c = __builtin_amdgcn_mfma_f32_16x16x32_bf16(ka1, qa1, c, 0, 0, 0);
            s4[tt] = c;
        }

        // banded bias (wave-uniform skip far from diagonal)
        {
            const int lgmin = l0 + rbase, lgmax = lgmin + 15;
            if (j0 + 63 >= lgmin - 4 && j0 <= lgmax + 4) {
#pragma unroll
                for (int tt = 0; tt < 4; ++tt) {
#pragma unroll
                    for (int r = 0; r < 4; ++r) {
                        const int key = j0 + tt * 16 + quad * 4 + r;
                        const int delta = key - lgq + 4;
                        if (delta >= 0 && delta <= 8) s4[tt][r] += bias_lds[qrow * 9 + delta];
                    }
                }
            }
        }

        // p = exp2(s*SC2 - ST2); accumulate l in-lane; cvt_pk pack -> b64 write
#pragma unroll
        for (int tt = 0; tt < 4; ++tt) {
            const float p0 = __builtin_amdgcn_exp2f(fmaf(s4[tt][0], SC2, -ST2));
            const float p1 = __builtin_amdgcn_exp2f(fmaf(s4[tt][1], SC2, -ST2));
            const float p2 = __builtin_amdgcn_exp2f(fmaf(s4[tt][2], SC2, -ST2));
            const float p3 = __builtin_amdgcn_exp2f(fmaf(s4[tt][3], SC2, -ST2));
            l_acc += (p0 + p1) + (p2 + p3);
            union { unsigned int w[2]; u16x4 u; } pk;
            pk.w[0] = cvt_pk_bf16(p0, p1);
            pk.w[1] = cvt_pk_bf16(p2, p3);
            *reinterpret_cast<u16x4*>(&pw[l16 * KSTRIDE + tt * 16 + quad * 4]) = pk.u;
        }
        // intra-wave P write->read: DS in-order, no barrier needed

        // PV: A = P[q][key], B = V[key][d] (vt layout [d][key], chunk-swizzled)
        const bf16x8 pa0 = *reinterpret_cast<const bf16x8*>(&pw[l16 * KSTRIDE + quad * 8]);
        const bf16x8 pa1 = *reinterpret_cast<const bf16x8*>(&pw[l16 * KSTRIDE + 32 + quad * 8]);
#pragma unroll
        for (int tt = 0; tt < 4; ++tt) {
            const int vrow = tt * 16 + l16;   // d
            const bf16x8 vb0 = *reinterpret_cast<const bf16x8*>(
                &vt[(vrow * 8 + (quad ^ (vrow & 7))) * 8]);
            const bf16x8 vb1 = *reinterpret_cast<const bf16x8*>(
                &vt[(vrow * 8 + ((quad + 4) ^ (vrow & 7))) * 8]);
            O[tt] = __builtin_amdgcn_mfma_f32_16x16x32_bf16(pa0, vb0, O[tt], 0, 0, 0);
            O[tt] = __builtin_amdgcn_mfma_f32_16x16x32_bf16(pa1, vb1, O[tt], 0, 0, 0);
        }
    }

    // reduce l across quads (disjoint key subsets): lanes with same l16 -> total
    float l_tot = l_acc;
    l_tot += __shfl_xor(l_tot, 16, 64);
    l_tot += __shfl_xor(l_tot, 32, 64);

    // band weights: p = exp((q.k_j + bias)*scale - STAB), OOB masked.
    // K rows read directly from Kt (just-touched, L2-hot).
    {
        union { bf16x8 v; u16x8 u; } a0, a1; a0.v = qa0; a1.v = qa1;
        float qf[16];
#pragma unroll
        for (int jj = 0; jj < 8; ++jj) { qf[jj] = bf2f(a0.u[jj]); qf[8 + jj] = bf2f(a1.u[jj]); }
        for (int dl = 0; dl < 9; ++dl) {
            const int jgl = lgq + dl - 4;
            const int jc = min(max(jgl, 0), LQ - 1);
            const u16* kr = Kb + (size_t)jc * CCH;
            union { bf16x8 v; u16x8 u; } k0, k1;
            k0.v = *reinterpret_cast<const bf16x8*>(kr + quad * 8);
            k1.v = *reinterpret_cast<const bf16x8*>(kr + 32 + quad * 8);
            float s = 0.f;
#pragma unroll
            for (int jj = 0; jj < 8; ++jj) {
                s += qf[jj]     * bf2f(k0.u[jj]);
                s += qf[8 + jj] * bf2f(k1.u[jj]);
            }
            s += __shfl_xor(s, 16, 64);
            s += __shfl_xor(s, 32, 64);
            float pband = 0.f;
            if (jgl >= 0 && jgl < LQ)
                pband = __builtin_amdgcn_exp2f(fmaf(s + bias_lds[qrow * 9 + dl], SC2, -ST2));
            if (quad == 0) bandw_lds[qrow * 9 + dl] = pband;
        }
    }
    // bandw: same-wave write->read, DS in-order.

    // fetch l for the O-rows this lane holds (q = quad*4+r): src lane has l16 = q
    float rinv[4];
#pragma unroll
    for (int r = 0; r < 4; ++r) {
        const int src = (lane & 48) | (quad * 4 + r);
        rinv[r] = 1.0f / __shfl(l_tot, src, 64);
    }

    // epilogue: (O + band.erv) * rinv -> resb bf16 [b][l][c]
#pragma unroll
    for (int tt = 0; tt < 4; ++tt) {
#pragma unroll
        for (int r = 0; r < 4; ++r) {
            const int row = rbase + quad * 4 + r;
            const int d = tt * 16 + l16;
            float val = O[tt][r];
#pragma unroll
            for (int dl = 0; dl < 9; ++dl)
                val += bandw_lds[row * 9 + dl] * erv_lds[dl * 64 + d];
            val *= rinv[r];
            resb[((size_t)b * LQ + (l0 + row)) * CCH + h * HD + d] = f2bf_u(val);
        }
    }
}

// ---------------------------------------------------------------------------
extern "C" void kernel_launch(void* const* d_in, const int* in_sizes, int n_in,
                              void* d_out, int out_size, void* d_ws, size_t ws_size,
                              hipStream_t stream) {
    const float* x   = (const float*)d_in[0];
    const float* wq  = (const float*)d_in[1];
    const float* bq  = (const float*)d_in[2];
    const float* wk  = (const float*)d_in[3];
    const float* bk  = (const float*)d_in[4];
    const float* wv  = (const float*)d_in[5];
    const float* bv  = (const float*)d_in[6];
    const float* wo  = (const float*)d_in[7];
    const float* bo  = (const float*)d_in[8];
    const float* erk = (const float*)d_in[9];
    const float* erv = (const float*)d_in[10];
    float* out = (float*)d_out;

    // ws (u16 units): xT | wb(4 mats) | Qw | Kt | Vw | resb  = ~36 MB
    const size_t NEL = (size_t)NB * CCH * LQ;   // 3,145,728
    u16* xT   = (u16*)d_ws;
    u16* wb   = xT + NEL;
    u16* Qw   = wb + (size_t)4 * WELE;
    u16* Kw   = Qw + NEL;   // Kt layout [b][l][c]
    u16* Vw   = Kw + NEL;
    u16* resb = Vw + NEL;

    prep_kernel<<<dim3(768 + 2304), 256, 0, stream>>>(x, wq, wk, wv, wo, wb, xT);
    proj_qkv_kernel<<<dim3(8, 12, 12), 512, 0, stream>>>(
        xT, wb, bq, bk, bv, Qw, Kw, Vw);
    attn_kernel<<<dim3(16, 12, 4), 256, 0, stream>>>(
        Qw, Kw, Vw, erk, erv, resb);
    proj_out_kernel<<<dim3(8, 12, 4), 512, 0, stream>>>(resb, wb, bo, out);
}

// Round 18
// 167.557 us; speedup vs baseline: 1.0293x; 1.0293x over previous
//
#include <hip/hip_runtime.h>

// Problem constants
#define NB   4
#define NH   12
#define HD   64
#define CCH  768        // NH*HD
#define LQ   1024
#define SCALE 0.125f    // 1/sqrt(64)
#define STAB  4.0f      // constant softmax stabilizer (scores ~N(0,1), max~4)
#define SC2  0.18033688f  // SCALE * log2(e)
#define ST2  5.7707802f   // STAB  * log2(e)
#define WELE (CCH*CCH)  // 589824 elements per weight matrix

typedef unsigned short u16;
typedef __bf16 bf16x8 __attribute__((ext_vector_type(8)));
typedef unsigned short u16x8 __attribute__((ext_vector_type(8)));
typedef unsigned short u16x4 __attribute__((ext_vector_type(4)));
typedef float floatx4 __attribute__((ext_vector_type(4)));

__device__ __forceinline__ float bf2f(u16 u) {
    union { unsigned int i; float f; } x; x.i = ((unsigned int)u) << 16; return x.f;
}
__device__ __forceinline__ u16 f2bf_u(float f) {
    union { float f; unsigned int i; } x; x.f = f;
    unsigned int i = x.i;
    return (u16)((i + 0x7FFFu + ((i >> 16) & 1u)) >> 16);   // RNE
}
// pack 2 f32 -> 2 bf16 (RNE), single HW instr (no builtin on gfx950; src0->lo)
__device__ __forceinline__ unsigned int cvt_pk_bf16(float a, float b) {
    unsigned int r;
    asm("v_cvt_pk_bf16_f32 %0, %1, %2" : "=v"(r) : "v"(a), "v"(b));
    return r;
}
// async global -> LDS, 16 B per lane; lds dst must be wave-uniform base
__device__ __forceinline__ void glds16(const u16* g, u16* l) {
    __builtin_amdgcn_global_load_lds(
        (const __attribute__((address_space(1))) unsigned int*)g,
        (__attribute__((address_space(3))) unsigned int*)l, 16, 0, 0);
}

// ---------------------------------------------------------------------------
// prep kernel: fused weight-convert + x-transpose (saves one launch gap).
//   blk <  768 : x [b][c][l] fp32 -> xT [b][l][c] bf16 (64x64 LDS transpose)
//   blk >= 768 : fp32 -> bf16 weight convert ([4][768*768]: wq,wk,wv,wo)
// ---------------------------------------------------------------------------
__global__ __launch_bounds__(256) void prep_kernel(
    const float* __restrict__ x,
    const float* __restrict__ wq, const float* __restrict__ wk,
    const float* __restrict__ wv, const float* __restrict__ wo,
    u16* __restrict__ wb, u16* __restrict__ xT)
{
    const int blk = blockIdx.x;
    const int t = threadIdx.x;
    if (blk < 768) {
        __shared__ u16 tile[64 * 68];
        const int l0 = (blk % 16) * 64, c0 = ((blk / 16) % 12) * 64, b = blk / 192;
        const float* xb = x + (size_t)b * CCH * LQ;
        {
            const int l = t & 63, cg = t >> 6;
            for (int i = 0; i < 16; ++i) {
                const int c = cg * 16 + i;
                tile[c * 68 + l] = f2bf_u(xb[(size_t)(c0 + c) * LQ + l0 + l]);
            }
        }
        __syncthreads();
        {
            const int c = t & 63, lg = t >> 6;
            for (int i = 0; i < 16; ++i) {
                const int l = lg * 16 + i;
                xT[((size_t)b * LQ + l0 + l) * CCH + c0 + c] = tile[c * 68 + l];
            }
        }
    } else {
        const int blk2 = blk - 768;
        const int p = blk2 / 576, bxi = blk2 % 576;
        const float* src = (p == 0) ? wq : (p == 1) ? wk : (p == 2) ? wv : wo;
        u16* dst = wb + (size_t)p * WELE;
        const int idx = (bxi * 256 + t) * 4;
        const float4 v = *reinterpret_cast<const float4*>(src + idx);
        u16x4 o;
        o[0] = f2bf_u(v.x); o[1] = f2bf_u(v.y); o[2] = f2bf_u(v.z); o[3] = f2bf_u(v.w);
        *reinterpret_cast<u16x4*>(dst + idx) = o;
    }
}

// ---------------------------------------------------------------------------
// Tiled MFMA GEMM core: Y = A (M x K) . B^T (N x K), both bf16 row-major-in-K.
// CTA (MI*32) x 128, BK=64, 8 waves (512 thr). glds16 staging, XOR-8 chunk
// swizzle, double-buffered, ONE barrier per K-step. Waves 2(m) x 4(n);
// wave tile (MI*16) x 32.  MI=2 -> 64x128 (LDS 48K, 3 CTA/CU = 24 waves/CU).
// ---------------------------------------------------------------------------
#define GEMM_STAGE(Ag, Bg, k0, abuf, bbuf, MI)                                \
    {                                                                         \
        _Pragma("unroll") for (int i = 0; i < (MI / 2); ++i) {                \
            const int sbase = (wave * (MI / 2) + i) * 64;                     \
            const int s = sbase + lane;                                       \
            const int m = s >> 3, pos = s & 7;                                \
            const int gpos = pos ^ (m & 7);                                   \
            glds16(Ag + (size_t)(m0 + m) * CCH + (k0) + gpos * 8,             \
                   &(abuf)[sbase * 8]);                                       \
        }                                                                     \
        _Pragma("unroll") for (int i = 0; i < 2; ++i) {                       \
            const int sbase = (wave * 2 + i) * 64;                            \
            const int s = sbase + lane;                                       \
            const int m = s >> 3, pos = s & 7;                                \
            const int gpos = pos ^ (m & 7);                                   \
            glds16(Bg + (size_t)(n0 + m) * CCH + (k0) + gpos * 8,             \
                   &(bbuf)[sbase * 8]);                                       \
        }                                                                     \
    }

#define GEMM_CORE(Ag, Bg, MI)                                                 \
    __shared__ __align__(16) u16 a_tile[2][(MI * 32) * 64];                   \
    __shared__ __align__(16) u16 b_tile[2][128 * 64];                         \
    const int t = threadIdx.x;                                                \
    const int wave = t >> 6, lane = t & 63;                                   \
    const int quad = lane >> 4, l16 = lane & 15;                              \
    const int wm = (wave >> 2) * (MI * 16), wn = (wave & 3) * 32;             \
    floatx4 acc[MI][2];                                                       \
    _Pragma("unroll") for (int mi = 0; mi < MI; ++mi)                         \
        _Pragma("unroll") for (int ni = 0; ni < 2; ++ni)                      \
            _Pragma("unroll") for (int r = 0; r < 4; ++r) acc[mi][ni][r] = 0.f;\
    GEMM_STAGE(Ag, Bg, 0, a_tile[0], b_tile[0], MI)                           \
    for (int kk = 0; kk < CCH / 64; ++kk) {                                   \
        __syncthreads();                                                      \
        if (kk + 1 < CCH / 64)                                                \
            GEMM_STAGE(Ag, Bg, (kk + 1) * 64,                                 \
                       a_tile[(kk + 1) & 1], b_tile[(kk + 1) & 1], MI)        \
        const u16* at = a_tile[kk & 1];                                       \
        const u16* bt = b_tile[kk & 1];                                       \
        bf16x8 af[2][MI], bfr[2][2];                                          \
        _Pragma("unroll") for (int s = 0; s < 2; ++s) {                       \
            _Pragma("unroll") for (int i = 0; i < MI; ++i) {                  \
                const int am = wm + i * 16 + l16;                             \
                const int c = s * 4 + quad;                                   \
                af[s][i]  = *reinterpret_cast<const bf16x8*>(                 \
                    &at[(am * 8 + (c ^ (am & 7))) * 8]);                      \
            }                                                                 \
            _Pragma("unroll") for (int j = 0; j < 2; ++j) {                   \
                const int bn = wn + j * 16 + l16;                             \
                const int c = s * 4 + quad;                                   \
                bfr[s][j] = *reinterpret_cast<const bf16x8*>(                 \
                    &bt[(bn * 8 + (c ^ (bn & 7))) * 8]);                      \
            }                                                                 \
        }                                                                     \
        _Pragma("unroll") for (int s = 0; s < 2; ++s)                         \
            _Pragma("unroll") for (int mi = 0; mi < MI; ++mi)                 \
                _Pragma("unroll") for (int ni = 0; ni < 2; ++ni)              \
                    acc[mi][ni] = __builtin_amdgcn_mfma_f32_16x16x32_bf16(    \
                        af[s][mi], bfr[s][ni], acc[mi][ni], 0, 0, 0);         \
    }

// proj_qkv (MI=2 M-split: 1152 CTAs, 3 CTA/CU, 24 waves/CU):
//   p==0 (Q), p==2 (V): A = wb[p] (o x c), B^T = xT[b] (l x c) -> Y [b][o][l]
//       96 tiles/GEMM = 12 M-tiles(64) x 8 N-tiles(128)
//   p==1 (K):           A = xT[b] (l x c), B^T = wb[1] (o x c) -> Kt [b][l][o]
//       96 tiles/GEMM = 16 M-tiles(64) x 6 N-tiles(128)
//   Chunked XCD swizzle (1152 = 8*144).
__global__ __launch_bounds__(512, 6) void proj_qkv_kernel(
    const u16* __restrict__ xT, const u16* __restrict__ wb,
    const float* __restrict__ bq, const float* __restrict__ bk,
    const float* __restrict__ bv,
    u16* __restrict__ Qw, u16* __restrict__ Kw, u16* __restrict__ Vw)
{
    const int wg0 = blockIdx.x + 8 * (blockIdx.y + 12 * blockIdx.z);
    const int swz = (wg0 & 7) * 144 + (wg0 >> 3);
    const int z = swz / 96, q = swz % 96;
    const int b = z / 3, p = z % 3;
    int m0, n0;
    const u16 *Ag, *Bg;
    if (p == 1) {
        m0 = (q / 6) * 64;                // L rows  (16 tiles)
        n0 = (q % 6) * 128;               // C cols  (6 tiles)
        Ag = xT + (size_t)b * LQ * CCH;
        Bg = wb + (size_t)WELE;
    } else {
        m0 = (q / 8) * 64;                // C rows  (12 tiles)
        n0 = (q % 8) * 128;               // L cols  (8 tiles)
        Ag = wb + (size_t)p * WELE;
        Bg = xT + (size_t)b * LQ * CCH;
    }

    GEMM_CORE(Ag, Bg, 2)

    if (p == 1) {
        u16* Y = Kw + (size_t)b * LQ * CCH;      // Kt [l][c]
#pragma unroll
        for (int mi = 0; mi < 2; ++mi) {
#pragma unroll
            for (int r = 0; r < 4; ++r) {
                const int l = m0 + wm + mi * 16 + quad * 4 + r;
#pragma unroll
                for (int ni = 0; ni < 2; ++ni) {
                    const int o = n0 + wn + ni * 16 + l16;
                    Y[(size_t)l * CCH + o] = f2bf_u(acc[mi][ni][r] + bk[o]);
                }
            }
        }
    } else {
        const float* bias = (p == 0) ? bq : bv;
        u16* Y = ((p == 0) ? Qw : Vw) + (size_t)b * CCH * LQ;
#pragma unroll
        for (int mi = 0; mi < 2; ++mi) {
#pragma unroll
            for (int r = 0; r < 4; ++r) {
                const int o = m0 + wm + mi * 16 + quad * 4 + r;
                const float bb = bias[o];
#pragma unroll
                for (int ni = 0; ni < 2; ++ni) {
                    const int l = n0 + wn + ni * 16 + l16;
                    Y[(size_t)o * LQ + l] = f2bf_u(acc[mi][ni][r] + bb);
                }
            }
        }
    }
}

// proj_out: A = wb[3], B^T = resb[b] ([l][c] bf16); out fp32 [b][c][l]
// M-split 64x128 tile (MI=2): 12 x 8 x 4 = 384 CTAs -> every CU covered.
__global__ __launch_bounds__(512) void proj_out_kernel(
    const u16* __restrict__ resb, const u16* __restrict__ wb,
    const float* __restrict__ bo, float* __restrict__ out)
{
    const int wg0 = blockIdx.x + 8 * (blockIdx.y + 12 * blockIdx.z);
    const int swz = (wg0 & 7) * 48 + (wg0 >> 3);
    const int bx = swz % 8, rest = swz / 8;
    const int by = rest % 12, b = rest / 12;
    const int n0 = bx * 128, m0 = by * 64;
    const u16* Ag = wb + (size_t)3 * WELE;
    const u16* Bg = resb + (size_t)b * LQ * CCH;
    float* Y = out + (size_t)b * CCH * LQ;

    GEMM_CORE(Ag, Bg, 2)

#pragma unroll
    for (int mi = 0; mi < 2; ++mi) {
#pragma unroll
        for (int r = 0; r < 4; ++r) {
            const int o = m0 + wm + mi * 16 + quad * 4 + r;
            const float bb = bo[o];
#pragma unroll
            for (int ni = 0; ni < 2; ++ni) {
                const int l = n0 + wn + ni * 16 + l16;
                Y[(size_t)o * LQ + l] = acc[mi][ni][r] + bb;
            }
        }
    }
}

// ---------------------------------------------------------------------------
// MFMA flash attention, S^T formulation + constant-stabilizer softmax.
//   (round-17 structure + FUSED BAND WEIGHTS: inside the banded-bias branch,
//   s4 after the bias add IS q.k+bias for the diagonal band, so pband =
//   exp2(s*SC2-ST2) is written to bandw_lds right there. The entire kdiag
//   epilogue (9 x (2 global loads + ~64 VALU + 2 shfl + exp) serial tail)
//   is deleted. bandw_lds zero-initialized before the first barrier to
//   cover OOB-masked entries. Writer uniqueness: each (qrow,delta) maps to
//   exactly one (key) lane/reg of the owning wave; epilogue reads are
//   same-wave (DS in-order), the contract bandw already used.)
//   K ([b][l][c] via proj swap) and V ([b][c][l]) staged via global_load_lds
//   into XOR-8-chunk-swizzled LDS, double-buffered, ONE barrier per iter.
//   XCD swizzle: all 16 q-blocks of one (b,h) land on one XCD (L2-resident).
//   p = exp2(s*SC2 - ST2); l accumulates per-lane; O accumulates with no
//   rescale (e^-STAB cancels in p/l). P via LDS (A-layout), PV = mfma(P, V).
// CTA = one (b,h) x 64 q-rows; 4 waves x 16 q. Key blocks of 64.
// ---------------------------------------------------------------------------
#define KSTRIDE 72
#define TILE_E  (64 * 64)   // u16 elements per K or V tile

// stage one 64x64 bf16 K tile + one 64x64 V tile: 16 glds16 calls split
// 4-per-wave (waves 0,1 -> K; waves 2,3 -> V). Chunk-swizzled source so the
// linear LDS destination holds chunk c of row m at slot c^(m&7).
__device__ __forceinline__ void stage_kv(
    const u16* __restrict__ Kb, const u16* __restrict__ Vb, int j0,
    u16* kb_lds, u16* vb_lds, int wave, int lane)
{
#pragma unroll
    for (int i = 0; i < 4; ++i) {
        const int sidx = wave * 4 + i;          // 0..15 (wave-uniform)
        if (sidx < 8) {
            const int sbase = sidx * 64;
            const int s = sbase + lane;
            const int m = s >> 3, pos = s & 7;  // key row, chunk slot
            const int gpos = pos ^ (m & 7);
            glds16(Kb + (size_t)(j0 + m) * CCH + gpos * 8, &kb_lds[sbase * 8]);
        } else {
            const int sbase = (sidx - 8) * 64;
            const int s = sbase + lane;
            const int m = s >> 3, pos = s & 7;  // d row, chunk slot
            const int gpos = pos ^ (m & 7);
            glds16(Vb + (size_t)m * LQ + j0 + gpos * 8, &vb_lds[sbase * 8]);
        }
    }
}

__global__ __launch_bounds__(256) void attn_kernel(
    const u16* __restrict__ Qw, const u16* __restrict__ Kt,
    const u16* __restrict__ Vw,
    const float* __restrict__ erk, const float* __restrict__ erv,
    u16* __restrict__ resb)
{
    __shared__ __align__(16) u16 kbuf[2 * TILE_E];   // [key][d] chunk-swizzled
    __shared__ __align__(16) u16 vbuf[2 * TILE_E];   // [d][key] chunk-swizzled
    __shared__ __align__(16) u16 p_lds[4 * 16 * KSTRIDE];
    __shared__ float bias_lds[64 * 9];
    __shared__ float bandw_lds[64 * 9];
    __shared__ float erk_lds[9 * 64];
    __shared__ float erv_lds[9 * 64];

    const int t = threadIdx.x;
    const int wave = t >> 6, lane = t & 63;
    const int quad = lane >> 4, l16 = lane & 15;
    // XCD-aware remap: q-blocks of one (b,h) share wgid residue mod 8
    const int wg = blockIdx.x + 16 * (blockIdx.y + 12 * blockIdx.z);
    const int rr = wg & 7, j = wg >> 3;
    const int l0 = (j & 15) * 64;
    const int hb = rr + 8 * (j >> 4);    // 0..47
    const int h = hb % NH, b = hb / NH;
    const int rbase = wave * 16;
    const size_t base = ((size_t)b * CCH + (size_t)h * HD) * LQ;
    const u16* Qb = Qw + base;
    const u16* Vb = Vw + base;
    const u16* Kb = Kt + (size_t)b * LQ * CCH + (size_t)h * HD;  // Kt rows

    for (int i = t; i < 9 * 64; i += 256) {
        erk_lds[i] = erk[(size_t)h * 9 * 64 + i];
        erv_lds[i] = erv[(size_t)h * 9 * 64 + i];
        bandw_lds[i] = 0.f;   // OOB band entries stay 0 (never written in loop)
    }

    // Q frags (serve as MFMA B operand): lane holds q-row = l16, d = quad*8+jj (+32)
    bf16x8 qa0, qa1;
    {
        const int lg = l0 + rbase + l16;
        union { u16x8 u; bf16x8 v; } t0, t1;
#pragma unroll
        for (int jj = 0; jj < 8; ++jj) {
            t0.u[jj] = Qb[(size_t)(quad * 8 + jj) * LQ + lg];
            t1.u[jj] = Qb[(size_t)(32 + quad * 8 + jj) * LQ + lg];
        }
        qa0 = t0.v; qa1 = t1.v;
    }

    // prologue: stage tile 0 into buf0 (drains at the erk barrier / first loop barrier)
    stage_kv(Kb, Vb, 0, kbuf, vbuf, wave, lane);

    __syncthreads();   // erk_lds + bandw zero-init ready + tile0 staged

    // bias_lds[row][dl] = q_row . erk[dl]
    {
        union { bf16x8 v; u16x8 u; } a0, a1; a0.v = qa0; a1.v = qa1;
        float qf[16];
#pragma unroll
        for (int jj = 0; jj < 8; ++jj) { qf[jj] = bf2f(a0.u[jj]); qf[8 + jj] = bf2f(a1.u[jj]); }
        for (int dl = 0; dl < 9; ++dl) {
            float s = 0.f;
#pragma unroll
            for (int jj = 0; jj < 8; ++jj) {
                s += qf[jj]     * erk_lds[dl * 64 + quad * 8 + jj];
                s += qf[8 + jj] * erk_lds[dl * 64 + 32 + quad * 8 + jj];
            }
            s += __shfl_xor(s, 16, 64);
            s += __shfl_xor(s, 32, 64);
            if (quad == 0) bias_lds[(rbase + l16) * 9 + dl] = s;
        }
    }

    // O[tt][r]: q = quad*4+r (wave-local), d = tt*16+l16.  l_acc: per-lane
    // partial softmax denom for q = l16 over this lane's key subset.
    floatx4 O[4];
    float l_acc = 0.f;
#pragma unroll
    for (int i = 0; i < 4; ++i)
#pragma unroll
        for (int r = 0; r < 4; ++r) O[i][r] = 0.f;

    u16* pw = p_lds + wave * 16 * KSTRIDE;
    const int qrow = rbase + l16;          // this lane's softmax q-row
    const int lgq = l0 + qrow;

    for (int kb = 0; kb < 16; ++kb) {
        const int j0 = kb * 64;
        // barrier: tile kb staged (vmcnt0 before s_barrier) + prev reads done
        __syncthreads();
        if (kb < 15)
            stage_kv(Kb, Vb, j0 + 64,
                     kbuf + ((kb + 1) & 1) * TILE_E,
                     vbuf + ((kb + 1) & 1) * TILE_E, wave, lane);
        const u16* kt = kbuf + (kb & 1) * TILE_E;
        const u16* vt = vbuf + (kb & 1) * TILE_E;

        // S^T = K.Q^T: 4 key tiles; C row = key = quad*4+r, col = q = l16
        floatx4 s4[4];
#pragma unroll
        for (int tt = 0; tt < 4; ++tt) {
            const int row = tt * 16 + l16;
            const bf16x8 ka0 = *reinterpret_cast<const bf16x8*>(
                &kt[(row * 8 + (quad ^ (row & 7))) * 8]);
            const bf16x8 ka1 = *reinterpret_cast<const bf16x8*>(
                &kt[(row * 8 + ((quad + 4) ^ (row & 7))) * 8]);
            floatx4 c;
#pragma unroll
            for (int r = 0; r < 4; ++r) c[r] = 0.f;
            c = __builtin_amdgcn_mfma_f32_16x16x32_bf16(ka0, qa0, c, 0, 0, 0);
            c = __builtin_amdgcn_mfma_f32_16x16x32_bf16(ka1, qa1, c, 0, 0, 0);
            s4[tt] = c;
        }

        // banded bias (wave-uniform skip far from diagonal) + FUSED band
        // weights: s4+bias here IS q.k+bias for the diagonal band, so pband
        // is computed and stored in the same place (epilogue deleted).
        {
            const int lgmin = l0 + rbase, lgmax = lgmin + 15;
            if (j0 + 63 >= lgmin - 4 && j0 <= lgmax + 4) {
#pragma unroll
                for (int tt = 0; tt < 4; ++tt) {
#pragma unroll
                    for (int r = 0; r < 4; ++r) {
                        const int key = j0 + tt * 16 + quad * 4 + r;
                        const int delta = key - lgq + 4;
                        if (delta >= 0 && delta <= 8) {
                            s4[tt][r] += bias_lds[qrow * 9 + delta];
                            bandw_lds[qrow * 9 + delta] =
                                __builtin_amdgcn_exp2f(fmaf(s4[tt][r], SC2, -ST2));
                        }
                    }
                }
            }
        }

        // p = exp2(s*SC2 - ST2); accumulate l in-lane; cvt_pk pack -> b64 write
#pragma unroll
        for (int tt = 0; tt < 4; ++tt) {
            const float p0 = __builtin_amdgcn_exp2f(fmaf(s4[tt][0], SC2, -ST2));
            const float p1 = __builtin_amdgcn_exp2f(fmaf(s4[tt][1], SC2, -ST2));
            const float p2 = __builtin_amdgcn_exp2f(fmaf(s4[tt][2], SC2, -ST2));
            const float p3 = __builtin_amdgcn_exp2f(fmaf(s4[tt][3], SC2, -ST2));
            l_acc += (p0 + p1) + (p2 + p3);
            union { unsigned int w[2]; u16x4 u; } pk;
            pk.w[0] = cvt_pk_bf16(p0, p1);
            pk.w[1] = cvt_pk_bf16(p2, p3);
            *reinterpret_cast<u16x4*>(&pw[l16 * KSTRIDE + tt * 16 + quad * 4]) = pk.u;
        }
        // intra-wave P write->read: DS in-order, no barrier needed

        // PV: A = P[q][key], B = V[key][d] (vt layout [d][key], chunk-swizzled)
        const bf16x8 pa0 = *reinterpret_cast<const bf16x8*>(&pw[l16 * KSTRIDE + quad * 8]);
        const bf16x8 pa1 = *reinterpret_cast<const bf16x8*>(&pw[l16 * KSTRIDE + 32 + quad * 8]);
#pragma unroll
        for (int tt = 0; tt < 4; ++tt) {
            const int vrow = tt * 16 + l16;   // d
            const bf16x8 vb0 = *reinterpret_cast<const bf16x8*>(
                &vt[(vrow * 8 + (quad ^ (vrow & 7))) * 8]);
            const bf16x8 vb1 = *reinterpret_cast<const bf16x8*>(
                &vt[(vrow * 8 + ((quad + 4) ^ (vrow & 7))) * 8]);
            O[tt] = __builtin_amdgcn_mfma_f32_16x16x32_bf16(pa0, vb0, O[tt], 0, 0, 0);
            O[tt] = __builtin_amdgcn_mfma_f32_16x16x32_bf16(pa1, vb1, O[tt], 0, 0, 0);
        }
    }

    // reduce l across quads (disjoint key subsets): lanes with same l16 -> total
    float l_tot = l_acc;
    l_tot += __shfl_xor(l_tot, 16, 64);
    l_tot += __shfl_xor(l_tot, 32, 64);

    // (band-weight epilogue deleted: bandw_lds was filled in the main loop
    //  by this wave's own lanes; same-wave DS write->read is in-order)

    // fetch l for the O-rows this lane holds (q = quad*4+r): src lane has l16 = q
    float rinv[4];
#pragma unroll
    for (int r = 0; r < 4; ++r) {
        const int src = (lane & 48) | (quad * 4 + r);
        rinv[r] = 1.0f / __shfl(l_tot, src, 64);
    }

    // epilogue: (O + band.erv) * rinv -> resb bf16 [b][l][c]
#pragma unroll
    for (int tt = 0; tt < 4; ++tt) {
#pragma unroll
        for (int r = 0; r < 4; ++r) {
            const int row = rbase + quad * 4 + r;
            const int d = tt * 16 + l16;
            float val = O[tt][r];
#pragma unroll
            for (int dl = 0; dl < 9; ++dl)
                val += bandw_lds[row * 9 + dl] * erv_lds[dl * 64 + d];
            val *= rinv[r];
            resb[((size_t)b * LQ + (l0 + row)) * CCH + h * HD + d] = f2bf_u(val);
        }
    }
}

// ---------------------------------------------------------------------------
extern "C" void kernel_launch(void* const* d_in, const int* in_sizes, int n_in,
                              void* d_out, int out_size, void* d_ws, size_t ws_size,
                              hipStream_t stream) {
    const float* x   = (const float*)d_in[0];
    const float* wq  = (const float*)d_in[1];
    const float* bq  = (const float*)d_in[2];
    const float* wk  = (const float*)d_in[3];
    const float* bk  = (const float*)d_in[4];
    const float* wv  = (const float*)d_in[5];
    const float* bv  = (const float*)d_in[6];
    const float* wo  = (const float*)d_in[7];
    const float* bo  = (const float*)d_in[8];
    const float* erk = (const float*)d_in[9];
    const float* erv = (const float*)d_in[10];
    float* out = (float*)d_out;

    // ws (u16 units): xT | wb(4 mats) | Qw | Kt | Vw | resb  = ~36 MB
    const size_t NEL = (size_t)NB * CCH * LQ;   // 3,145,728
    u16* xT   = (u16*)d_ws;
    u16* wb   = xT + NEL;
    u16* Qw   = wb + (size_t)4 * WELE;
    u16* Kw   = Qw + NEL;   // Kt layout [b][l][c]
    u16* Vw   = Kw + NEL;
    u16* resb = Vw + NEL;

    prep_kernel<<<dim3(768 + 2304), 256, 0, stream>>>(x, wq, wk, wv, wo, wb, xT);
    proj_qkv_kernel<<<dim3(8, 12, 12), 512, 0, stream>>>(
        xT, wb, bq, bk, bv, Qw, Kw, Vw);
    attn_kernel<<<dim3(16, 12, 4), 256, 0, stream>>>(
        Qw, Kw, Vw, erk, erv, resb);
    proj_out_kernel<<<dim3(8, 12, 4), 512, 0, stream>>>(resb, wb, bo, out);
}